// Round 5
// baseline (111.921 us; speedup 1.0000x reference)
//
#include <hip/hip_runtime.h>
#include <math.h>

// CapsuleLayer dynamic routing, MI355X — fused recompute structure.
// B=128, R=4096, IN=16, OUT=32, C=2, 3 routing iterations.
//
// KEY INSIGHT (R5): priors are never materialized. Logits are linear in the
// running v-sum (L_k = p . (v0+..+v_{k-1})), and iteration 0's softmax is
// uniform == exp(p . 0). So all 3 iterations are the SAME kernel:
//   pass: recompute p = x.W row-wise (f16 pk math), e = exp(p.vsum),
//         acc += e*p, esum += e   -> per-(block,b) partials (8.4 MB total)
//   redv: reduce partials over r-chunk blocks, squash, vsum += v (or out).
// This removes the 201 MB priors round-trip (write + 2 reads) that R1-R4
// paid, replacing it with 2 extra GEMM recomputes (~10 us issue each).
#define CB    128
#define CR    4096
#define CIN   16
#define COUT  32
#define CCAP  2
#define RCH   16            // r rows per pass block
#define NRCH  (CR / RCH)    // 256 r-chunks
#define EPSF  1e-12f

typedef _Float16 h8  __attribute__((ext_vector_type(8)));
typedef float    f8v __attribute__((ext_vector_type(8)));

static __device__ __forceinline__ h8 splat8(_Float16 v) {
  h8 r = {v, v, v, v, v, v, v, v};
  return r;
}

// zero vsum (2*128*32 floats) — must run every launch (harness poisons ws).
__global__ __launch_bounds__(256) void caps_init_kernel(float* __restrict__ vsum)
{
  vsum[blockIdx.x * 256 + threadIdx.x] = 0.f;
}

// ---------------------------------------------------------------------------
// pass: grid = C*NRCH = 512 blocks, 512 threads.
// t = rsub(2) x b(128) x og(2): thread owns (b, 16 o's), 8 rows.
// W tile (16 r) staged f32->f16 to LDS once (one barrier), then a
// barrier-free 8-row loop: f16 pk-FMA GEMM + exp + accumulate in regs.
// 2-way split f16 accumulators (chain<=8) + f32 combine for precision.
// ---------------------------------------------------------------------------
__global__ __launch_bounds__(512) void caps_pass_kernel(
    const float* __restrict__ x, const float* __restrict__ w,
    const float* __restrict__ vsum,
    float* __restrict__ partialA, float* __restrict__ partialE)
{
  const int blk  = (int)blockIdx.x;
  const int c    = blk >> 8;          // 0..1
  const int rch  = blk & 255;         // 0..255
  const int r0   = rch * RCH;
  const int t    = (int)threadIdx.x;
  const int rsub = t >> 8;            // 0..1 (rows 0-7 / 8-15 of chunk)
  const int tt   = t & 255;
  const int b    = tt >> 1;           // 0..127
  const int og   = tt & 1;
  const int o0   = og * 16;

  __shared__ __align__(16) _Float16 Wl[RCH * CIN * COUT];  // 16 KB f16
  __shared__ float accH[256][17];                          // 17 KB

  // ---- stage W tile: 16 r x 512 f32 -> f16 LDS; 16 values per thread ----
  {
    const float4* wp = (const float4*)(w + ((size_t)c * CR + r0) * (CIN * COUT)) + t * 4;
    float4 q0 = wp[0], q1 = wp[1], q2 = wp[2], q3 = wp[3];
    float tmp[16] = {q0.x, q0.y, q0.z, q0.w, q1.x, q1.y, q1.z, q1.w,
                     q2.x, q2.y, q2.z, q2.w, q3.x, q3.y, q3.z, q3.w};
    h8 lo, hi;
#pragma unroll
    for (int j = 0; j < 8; ++j) { lo[j] = (_Float16)tmp[j]; hi[j] = (_Float16)tmp[j + 8]; }
    h8* wl8 = (h8*)(Wl + t * 16);
    wl8[0] = lo;
    wl8[1] = hi;
  }

  // ---- per-thread v slice (16 o's) ----
  float v[16];
  {
    const float4* vp = (const float4*)(vsum + ((size_t)(c * CB + b)) * COUT + o0);
#pragma unroll
    for (int k = 0; k < 4; ++k) {
      float4 q = vp[k];
      v[4 * k] = q.x; v[4 * k + 1] = q.y; v[4 * k + 2] = q.z; v[4 * k + 3] = q.w;
    }
  }

  float acc[16];
#pragma unroll
  for (int j = 0; j < 16; ++j) acc[j] = 0.f;
  float esum = 0.f;

  __syncthreads();

  // ---- 8-row main loop, no barriers ----
#pragma unroll
  for (int rr = 0; rr < 8; ++rr) {
    const int ri = rsub * 8 + rr;           // row within chunk
    const int r  = r0 + ri;
    const float4* xp = (const float4*)(x + ((size_t)b * CR + r) * CIN);
    float4 x0 = xp[0], x1 = xp[1], x2 = xp[2], x3 = xp[3];
    float xs[16] = {x0.x, x0.y, x0.z, x0.w, x1.x, x1.y, x1.z, x1.w,
                    x2.x, x2.y, x2.z, x2.w, x3.x, x3.y, x3.z, x3.w};
    _Float16 hx[16];
#pragma unroll
    for (int i = 0; i < 16; ++i) hx[i] = (_Float16)xs[i];

    // W row slice for this thread's 16 o's: h8 index (ri*512 + i*32 + o0)/8
    const h8* wrow = (const h8*)(Wl + ri * (CIN * COUT) + o0);

    h8 pa0 = {}, pa1 = {}, pb0 = {}, pb1 = {};
#pragma unroll
    for (int i = 0; i < 8; ++i) {
      h8 s = splat8(hx[i]);
      pa0 += s * wrow[i * 4];       // o0..o0+7
      pb0 += s * wrow[i * 4 + 1];   // o0+8..o0+15
    }
#pragma unroll
    for (int i = 8; i < 16; ++i) {
      h8 s = splat8(hx[i]);
      pa1 += s * wrow[i * 4];
      pb1 += s * wrow[i * 4 + 1];
    }
    f8v pA = __builtin_convertvector(pa0, f8v) + __builtin_convertvector(pa1, f8v);
    f8v pB = __builtin_convertvector(pb0, f8v) + __builtin_convertvector(pb1, f8v);

    float d = 0.f;
#pragma unroll
    for (int j = 0; j < 8; ++j) d += pA[j] * v[j] + pB[j] * v[j + 8];
    d += __shfl_xor(d, 1);          // og-pair combine -> full 32-o dot
    const float e = __expf(d);      // it0: vsum=0 -> e=1 (uniform softmax)
    esum += e;
#pragma unroll
    for (int j = 0; j < 8; ++j) { acc[j] += e * pA[j]; acc[j + 8] += e * pB[j]; }
  }

  // ---- combine rsub halves via LDS, store partials ----
  if (rsub == 1) {
#pragma unroll
    for (int j = 0; j < 16; ++j) accH[tt][j] = acc[j];
    accH[tt][16] = esum;
  }
  __syncthreads();
  if (rsub == 0) {
#pragma unroll
    for (int j = 0; j < 16; ++j) acc[j] += accH[tt][j];
    esum += accH[tt][16];
    float* pA_ = partialA + (((size_t)(c * NRCH + rch)) * CB + b) * COUT + o0;
#pragma unroll
    for (int j = 0; j < 16; ++j) pA_[j] = acc[j];
    if (og == 0) partialE[((size_t)(c * NRCH + rch)) * CB + b] = esum;
  }
}

// ---------------------------------------------------------------------------
// redv: per (c,b) reduce 256 chunk-partials -> v = squash(s/esum);
// vsum += v, or write out on the final iteration. grid 256 x 256 threads.
// ---------------------------------------------------------------------------
__global__ __launch_bounds__(256) void caps_redv_kernel(
    const float* __restrict__ partialA, const float* __restrict__ partialE,
    float* __restrict__ vsum, float* __restrict__ out, int final_)
{
  const int cb = (int)blockIdx.x;
  const int c  = cb >> 7, b = cb & 127;
  const int t  = (int)threadIdx.x;
  const int o  = t & 31, jg = t >> 5;      // 8 j-groups

  __shared__ float red[8][33];
  __shared__ float rede[8];

  float s = 0.f;
#pragma unroll 4
  for (int k = 0; k < 32; ++k) {
    const int j = jg + k * 8;
    s += partialA[(((size_t)(c * NRCH + j)) * CB + b) * COUT + o];
  }
  red[jg][o] = s;
  __syncthreads();

  if (t < 8) {
    float e = 0.f;
#pragma unroll 4
    for (int k = 0; k < 32; ++k)
      e += partialE[((size_t)(c * NRCH + t + k * 8)) * CB + b];
    rede[t] = e;
  }
  __syncthreads();

  if (t < 32) {
    float sv = red[0][t] + red[1][t] + red[2][t] + red[3][t] +
               red[4][t] + red[5][t] + red[6][t] + red[7][t];
    float es = rede[0] + rede[1] + rede[2] + rede[3] +
               rede[4] + rede[5] + rede[6] + rede[7];
    float sm = sv / es;
    float sn = sm * sm;
#pragma unroll
    for (int sh = 1; sh < 32; sh <<= 1) sn += __shfl_xor(sn, sh);
    float fac = sn / ((1.f + sn + EPSF) * sqrtf(sn + EPSF));
    float vv = sm * fac;
    if (final_) out[cb * COUT + t] = vv;
    else        vsum[cb * COUT + t] += vv;
  }
}

extern "C" void kernel_launch(void* const* d_in, const int* in_sizes, int n_in,
                              void* d_out, int out_size, void* d_ws, size_t ws_size,
                              hipStream_t stream) {
  const float* x = (const float*)d_in[0];
  const float* w = (const float*)d_in[1];
  float* out = (float*)d_out;

  char* p = (char*)d_ws;
  float* vsum = (float*)p;                         // 32,768 B
  p += (size_t)CCAP * CB * COUT * sizeof(float);
  float* partialA = (float*)p;                     // 2*256*128*32*4 = 8,388,608 B
  p += (size_t)CCAP * NRCH * CB * COUT * sizeof(float);
  float* partialE = (float*)p;                     // 2*256*128*4 = 262,144 B

  caps_init_kernel<<<dim3(32), 256, 0, stream>>>(vsum);
  for (int it = 0; it < 3; ++it) {
    caps_pass_kernel<<<dim3(CCAP * NRCH), 512, 0, stream>>>(x, w, vsum, partialA, partialE);
    caps_redv_kernel<<<dim3(CCAP * CB), 256, 0, stream>>>(partialA, partialE, vsum, out,
                                                          it == 2 ? 1 : 0);
  }
}

// Round 6
// 75.452 us; speedup vs baseline: 1.4833x; 1.4833x over previous
//
#include <hip/hip_runtime.h>
#include <math.h>

// CapsuleLayer dynamic routing, MI355X — fused recompute + MFMA.
// B=128, R=4096, IN=16, OUT=32, C=2, 3 routing iterations.
//
// Structure (R5, kept): priors never materialized; logits linear in the
// running v-sum, so all 3 iterations run the same pass kernel:
//   e = exp(p . vsum), acc += e*p, esum += e  -> chunk partials -> redv.
// New in R6: the per-r GEMM p = x.W runs on MFMA 16x16x32_f16 with
//   A = W^T frag (m=o), B = x frag (n=b), D[m=o][n=b].
// k-slot safety: mfma pairs A-slot (g,j) with B-slot (g,j); both operands
// put i=4*g+j in elements 0..3 and ZEROS in 4..7, so the exact k<->slot
// hardware mapping cancels. C/D layout is m89-verified:
//   col(n)=lane&15, row(m)=4*(lane>>4)+reg.
#define CB    128
#define CR    4096
#define CIN   16
#define COUT  32
#define CCAP  2
#define RC    16            // r rows per pass block
#define NRCH  (CR / RC)     // 256 chunks
#define EPSF  1e-12f

typedef _Float16 h8  __attribute__((ext_vector_type(8)));
typedef _Float16 h4t __attribute__((ext_vector_type(4)));
typedef float    f4  __attribute__((ext_vector_type(4)));

// zero vsum (2*128*32 floats) — ws is poisoned, must re-init every launch.
__global__ __launch_bounds__(256) void caps_init_kernel(float* __restrict__ vsum)
{
  vsum[blockIdx.x * 256 + threadIdx.x] = 0.f;
}

// ---------------------------------------------------------------------------
// prepack: Wp[c][r][ot][L][j] = (f16) W[c][r][ 4*(L>>4)+j ][ ot*16 + (L&15) ]
// (A-fragment order for mfma, elements j=0..3; zeros are added at load time)
// grid = C*R/4 = 2048 blocks, 256 threads, 4 W-rows per block.
// ---------------------------------------------------------------------------
__global__ __launch_bounds__(256) void caps_prepack_kernel(
    const float* __restrict__ w, _Float16* __restrict__ wp)
{
  const int blk = (int)blockIdx.x;
  const int c   = blk >> 10;
  const int r0  = (blk & 1023) * 4;
  const int t   = (int)threadIdx.x;

  __shared__ __align__(16) float Wl[4 * 512];   // 8 KB
  {
    const float4* src = (const float4*)(w + ((size_t)c * CR + r0) * 512);
    ((float4*)Wl)[t]       = src[t];
    ((float4*)Wl)[t + 256] = src[t + 256];
  }
  __syncthreads();

#pragma unroll
  for (int s = 0; s < 2; ++s) {
    const int idx = t + s * 256;
    const int rr  = idx >> 7;
    const int rem = idx & 127;
    const int ot  = rem >> 6;
    const int L   = rem & 63;
    const int g   = L >> 4, m = L & 15;
    h4t v;
#pragma unroll
    for (int j = 0; j < 4; ++j)
      v[j] = (_Float16)Wl[rr * 512 + (4 * g + j) * 32 + ot * 16 + m];
    *(h4t*)(wp + ((((size_t)(c * CR + r0 + rr)) * 2 + ot) * 64 + L) * 4) = v;
  }
}

// ---------------------------------------------------------------------------
// pass: grid = C*NRCH = 512 blocks, 512 threads = 8 waves (b-tiles of 16).
// Per r: 2 mfma (o-tiles) -> P[o][b] frags; d = P.v via 8 FMA + 2 shfl_xor;
// e = exp(d); acc[frag] += e*P; esum += e. Epilogue: LDS transpose ->
// coalesced partial stores (same layout as R5's proven redv).
// ---------------------------------------------------------------------------
__global__ __launch_bounds__(512) void caps_pass_kernel(
    const float* __restrict__ x, const _Float16* __restrict__ wp,
    const float* __restrict__ vsum,
    float* __restrict__ partialA, float* __restrict__ partialE)
{
  const int blk = (int)blockIdx.x;
  const int c   = blk >> 8;
  const int rch = blk & 255;
  const int r0  = rch * RC;
  const int t   = (int)threadIdx.x;
  const int wv  = t >> 6;        // wave id 0..7 -> b-tile
  const int L   = t & 63;
  const int g   = L >> 4;        // lane group
  const int m   = L & 15;
  const int b   = wv * 16 + m;   // this lane's b column

  __shared__ __align__(16) _Float16 WpL[RC * 512];   // 16 KB frag-order chunk
  __shared__ float OutL[128][40];                    // 20 KB transpose buffer

  // ---- stage Wp chunk (16 KB contiguous), coalesced ----
  {
    const int4* src = (const int4*)(wp + (size_t)(c * CR + r0) * 512);
    ((int4*)WpL)[t]       = src[t];
    ((int4*)WpL)[t + 512] = src[t + 512];
  }

  // ---- per-lane v slices: v[b][4g..4g+3] and v[b][16+4g..] ----
  const float* vb = vsum + ((size_t)c * CB + b) * COUT;
  float4 vA = *(const float4*)(vb + 4 * g);
  float4 vB = *(const float4*)(vb + 16 + 4 * g);

  float accA[4] = {0.f, 0.f, 0.f, 0.f};
  float accB[4] = {0.f, 0.f, 0.f, 0.f};
  float esum = 0.f;

  __syncthreads();

#pragma unroll 4
  for (int ri = 0; ri < RC; ++ri) {
    const int r = r0 + ri;
    // B-frag: x[b][r][4g..4g+3] -> elements 0..3, zeros 4..7
    float4 xf = *(const float4*)(x + ((size_t)b * CR + r) * CIN + 4 * g);
    h8 bx = {(_Float16)xf.x, (_Float16)xf.y, (_Float16)xf.z, (_Float16)xf.w,
             (_Float16)0.f, (_Float16)0.f, (_Float16)0.f, (_Float16)0.f};
    // A-frags from LDS (8 B each, conflict-free)
    h4t wA4 = *(const h4t*)(WpL + ri * 512 + L * 4);
    h4t wB4 = *(const h4t*)(WpL + ri * 512 + 256 + L * 4);
    h8 aA = {wA4[0], wA4[1], wA4[2], wA4[3],
             (_Float16)0.f, (_Float16)0.f, (_Float16)0.f, (_Float16)0.f};
    h8 aB = {wB4[0], wB4[1], wB4[2], wB4[3],
             (_Float16)0.f, (_Float16)0.f, (_Float16)0.f, (_Float16)0.f};
    f4 z = {0.f, 0.f, 0.f, 0.f};
    f4 pA = __builtin_amdgcn_mfma_f32_16x16x32_f16(aA, bx, z, 0, 0, 0);
    f4 pB = __builtin_amdgcn_mfma_f32_16x16x32_f16(aB, bx, z, 0, 0, 0);

    // dot over o: in-lane partial (this lane's 8 o's), then sum over groups
    float d = pA[0] * vA.x + pA[1] * vA.y + pA[2] * vA.z + pA[3] * vA.w
            + pB[0] * vB.x + pB[1] * vB.y + pB[2] * vB.z + pB[3] * vB.w;
    d += __shfl_xor(d, 16);
    d += __shfl_xor(d, 32);

    const float e = __expf(d);   // it0: vsum=0 -> e=1 (uniform softmax)
    esum += e;
#pragma unroll
    for (int j = 0; j < 4; ++j) { accA[j] += e * pA[j]; accB[j] += e * pB[j]; }
  }

  // ---- fragment -> LDS transpose ----
#pragma unroll
  for (int j = 0; j < 4; ++j) {
    OutL[b][4 * g + j]      = accA[j];
    OutL[b][16 + 4 * g + j] = accB[j];
  }
  if (g == 0) OutL[b][32] = esum;
  __syncthreads();

  // ---- coalesced partial stores (layout matches R5 redv) ----
  {
    const int bb = t >> 2, q = t & 3;
    float4 v0 = *(const float4*)&OutL[bb][q * 8];
    float4 v1 = *(const float4*)&OutL[bb][q * 8 + 4];
    float* dst = partialA + (((size_t)(c * NRCH + rch)) * CB + bb) * COUT + q * 8;
    *(float4*)dst = v0;
    *(float4*)(dst + 4) = v1;
    if (t < 128) partialE[((size_t)(c * NRCH + rch)) * CB + t] = OutL[t][32];
  }
}

// ---------------------------------------------------------------------------
// redv (R5, proven): reduce 256 chunk-partials -> v = squash(s/esum);
// vsum += v, or write out on the final iteration. grid 256 x 256 threads.
// ---------------------------------------------------------------------------
__global__ __launch_bounds__(256) void caps_redv_kernel(
    const float* __restrict__ partialA, const float* __restrict__ partialE,
    float* __restrict__ vsum, float* __restrict__ out, int final_)
{
  const int cb = (int)blockIdx.x;
  const int c  = cb >> 7, b = cb & 127;
  const int t  = (int)threadIdx.x;
  const int o  = t & 31, jg = t >> 5;      // 8 j-groups

  __shared__ float red[8][33];
  __shared__ float rede[8];

  float s = 0.f;
#pragma unroll 4
  for (int k = 0; k < 32; ++k) {
    const int j = jg + k * 8;
    s += partialA[(((size_t)(c * NRCH + j)) * CB + b) * COUT + o];
  }
  red[jg][o] = s;
  __syncthreads();

  if (t < 8) {
    float e = 0.f;
#pragma unroll 4
    for (int k = 0; k < 32; ++k)
      e += partialE[((size_t)(c * NRCH + t + k * 8)) * CB + b];
    rede[t] = e;
  }
  __syncthreads();

  if (t < 32) {
    float sv = red[0][t] + red[1][t] + red[2][t] + red[3][t] +
               red[4][t] + red[5][t] + red[6][t] + red[7][t];
    float es = rede[0] + rede[1] + rede[2] + rede[3] +
               rede[4] + rede[5] + rede[6] + rede[7];
    float sm = sv / es;
    float sn = sm * sm;
#pragma unroll
    for (int sh = 1; sh < 32; sh <<= 1) sn += __shfl_xor(sn, sh);
    float fac = sn / ((1.f + sn + EPSF) * sqrtf(sn + EPSF));
    float vv = sm * fac;
    if (final_) out[cb * COUT + t] = vv;
    else        vsum[cb * COUT + t] += vv;
  }
}

extern "C" void kernel_launch(void* const* d_in, const int* in_sizes, int n_in,
                              void* d_out, int out_size, void* d_ws, size_t ws_size,
                              hipStream_t stream) {
  const float* x = (const float*)d_in[0];
  const float* w = (const float*)d_in[1];
  float* out = (float*)d_out;

  char* p = (char*)d_ws;
  _Float16* wp = (_Float16*)p;                     // 2*4096*512 f16 = 8,388,608 B
  p += (size_t)CCAP * CR * 512 * sizeof(_Float16);
  float* vsum = (float*)p;                         // 32,768 B
  p += (size_t)CCAP * CB * COUT * sizeof(float);
  float* partialA = (float*)p;                     // 8,388,608 B
  p += (size_t)CCAP * NRCH * CB * COUT * sizeof(float);
  float* partialE = (float*)p;                     // 262,144 B

  caps_prepack_kernel<<<dim3(CCAP * 1024), 256, 0, stream>>>(w, wp);
  caps_init_kernel<<<dim3(32), 256, 0, stream>>>(vsum);
  for (int it = 0; it < 3; ++it) {
    caps_pass_kernel<<<dim3(CCAP * NRCH), 512, 0, stream>>>(x, wp, vsum, partialA, partialE);
    caps_redv_kernel<<<dim3(CCAP * CB), 256, 0, stream>>>(partialA, partialE, vsum, out,
                                                          it == 2 ? 1 : 0);
  }
}

// Round 7
// 71.646 us; speedup vs baseline: 1.5621x; 1.0531x over previous
//
#include <hip/hip_runtime.h>
#include <math.h>

// CapsuleLayer dynamic routing, MI355X — fused recompute + MFMA, R7.
// B=128, R=4096, IN=16, OUT=32, C=2, 3 routing iterations.
//
// Structure: priors never materialized; logits linear in the running v-sum,
// so all 3 iterations run the same pass kernel:
//   p = x.W per row via mfma_f32_16x16x32_f16 (A=W^T frag m=o, B=x frag n=b)
//   e = exp(p . vsum)  [it0: e=1, uniform softmax]
//   acc += e*p, esum += e  -> chunk partials -> redv (squash, vsum update).
// R7: prepack and init kernels deleted. W is staged f32->LDS and packed to
// fragment order IN-LDS per block (same index formula as the old prepack,
// main loop unchanged). redv mode: 0 first (vsum=v), 1 mid (+=), 2 final(out).
// k-slot safety (HW-verified R6, absmax 0.0039): both mfma operands put
// i=4*(L>>4)+j in elements 0..3 and zeros in 4..7 -> k mapping cancels.
// C/D layout (m89-verified): col(n)=lane&15, row(m)=4*(lane>>4)+reg.
#define CB    128
#define CR    4096
#define CIN   16
#define COUT  32
#define CCAP  2
#define RC    16            // r rows per pass block
#define NRCH  (CR / RC)     // 256 chunks
#define EPSF  1e-12f

typedef _Float16 h8  __attribute__((ext_vector_type(8)));
typedef _Float16 h4t __attribute__((ext_vector_type(4)));
typedef float    f4  __attribute__((ext_vector_type(4)));

// ---------------------------------------------------------------------------
// pass: grid = C*NRCH = 512 blocks, 512 threads = 8 waves (b-tiles of 16).
// Startup: stage 16 W rows (32 KB f32) coalesced -> LDS, pack to fragment
// order (16 KB f16) in the same LDS bytes. Then a barrier-free 16-r loop:
// per r: 2 mfma -> P[o][b] frags; d = P.v (8 FMA + 2 shfl_xor); e = exp(d);
// acc += e*P. Epilogue: LDS transpose -> coalesced partial stores.
// ---------------------------------------------------------------------------
__global__ __launch_bounds__(512) void caps_pass_kernel(
    const float* __restrict__ x, const float* __restrict__ w,
    const float* __restrict__ vsum,
    float* __restrict__ partialA, float* __restrict__ partialE,
    int uniform)
{
  const int blk = (int)blockIdx.x;
  const int c   = blk >> 8;
  const int rch = blk & 255;
  const int r0  = rch * RC;
  const int t   = (int)threadIdx.x;
  const int wv  = t >> 6;        // wave id 0..7 -> b-tile
  const int L   = t & 63;
  const int g   = L >> 4;        // lane k-group
  const int m   = L & 15;
  const int b   = wv * 16 + m;   // this lane's b column

  // LDS overlay: [0,32768) f32 W stage (startup only);
  //              [0,16384) packed f16 frags; [16384,36864) OutL transpose.
  __shared__ __align__(16) char lds[36864];
  float*    Wst = (float*)lds;
  _Float16* WpL = (_Float16*)lds;
  float (*OutL)[40] = (float (*)[40])(lds + 16384);

  // ---- stage 16 W rows, coalesced: 8192 f32 = 512 thr x 4 float4 ----
  {
    const float4* src = (const float4*)(w + ((size_t)c * CR + r0) * 512);
#pragma unroll
    for (int k = 0; k < 4; ++k) ((float4*)Wst)[t + k * 512] = src[t + k * 512];
  }
  __syncthreads();

  // ---- pack to fragment order (same formula as R6 prepack):
  // slot sl=(r,ot,L'): WpL[sl*4+j] = Wst[r*512 + (4g'+j)*32 + ot*16 + m'] ----
  h4t pk[4];
#pragma unroll
  for (int q = 0; q < 4; ++q) {
    const int sl  = t * 4 + q;
    const int rr  = sl >> 7;
    const int rem = sl & 127;
    const int ot  = rem >> 6;
    const int Ls  = rem & 63;
    const int gs  = Ls >> 4, ms = Ls & 15;
#pragma unroll
    for (int j = 0; j < 4; ++j)
      pk[q][j] = (_Float16)Wst[rr * 512 + (4 * gs + j) * 32 + ot * 16 + ms];
  }
  __syncthreads();   // all reads of Wst done
#pragma unroll
  for (int q = 0; q < 4; ++q) ((h4t*)WpL)[t * 4 + q] = pk[q];

  // ---- per-lane v slices (skip on uniform pass: buffer may be poison) ----
  float4 vA = {0.f, 0.f, 0.f, 0.f}, vB = {0.f, 0.f, 0.f, 0.f};
  if (!uniform) {
    const float* vb = vsum + ((size_t)c * CB + b) * COUT;
    vA = *(const float4*)(vb + 4 * g);
    vB = *(const float4*)(vb + 16 + 4 * g);
  }

  float accA[4] = {0.f, 0.f, 0.f, 0.f};
  float accB[4] = {0.f, 0.f, 0.f, 0.f};
  float esum = 0.f;

  __syncthreads();   // packed W visible to all

#pragma unroll 4
  for (int ri = 0; ri < RC; ++ri) {
    const int r = r0 + ri;
    // B-frag: x[b][r][4g..4g+3] -> elements 0..3, zeros 4..7
    float4 xf = *(const float4*)(x + ((size_t)b * CR + r) * CIN + 4 * g);
    h8 bx = {(_Float16)xf.x, (_Float16)xf.y, (_Float16)xf.z, (_Float16)xf.w,
             (_Float16)0.f, (_Float16)0.f, (_Float16)0.f, (_Float16)0.f};
    // A-frags from LDS (8 B each, conflict-free)
    h4t wA4 = *(const h4t*)(WpL + ri * 512 + L * 4);
    h4t wB4 = *(const h4t*)(WpL + ri * 512 + 256 + L * 4);
    h8 aA = {wA4[0], wA4[1], wA4[2], wA4[3],
             (_Float16)0.f, (_Float16)0.f, (_Float16)0.f, (_Float16)0.f};
    h8 aB = {wB4[0], wB4[1], wB4[2], wB4[3],
             (_Float16)0.f, (_Float16)0.f, (_Float16)0.f, (_Float16)0.f};
    f4 z = {0.f, 0.f, 0.f, 0.f};
    f4 pA = __builtin_amdgcn_mfma_f32_16x16x32_f16(aA, bx, z, 0, 0, 0);
    f4 pB = __builtin_amdgcn_mfma_f32_16x16x32_f16(aB, bx, z, 0, 0, 0);

    float e;
    if (uniform) {
      e = 1.f;                   // it0: softmax over zero logits
    } else {
      float d = pA[0] * vA.x + pA[1] * vA.y + pA[2] * vA.z + pA[3] * vA.w
              + pB[0] * vB.x + pB[1] * vB.y + pB[2] * vB.z + pB[3] * vB.w;
      d += __shfl_xor(d, 16);
      d += __shfl_xor(d, 32);
      e = __expf(d);
    }
    esum += e;
#pragma unroll
    for (int j = 0; j < 4; ++j) { accA[j] += e * pA[j]; accB[j] += e * pB[j]; }
  }

  // ---- fragment -> LDS transpose ----
#pragma unroll
  for (int j = 0; j < 4; ++j) {
    OutL[b][4 * g + j]      = accA[j];
    OutL[b][16 + 4 * g + j] = accB[j];
  }
  if (g == 0) OutL[b][32] = esum;
  __syncthreads();

  // ---- coalesced partial stores ----
  {
    const int bb = t >> 2, q = t & 3;
    float4 v0 = *(const float4*)&OutL[bb][q * 8];
    float4 v1 = *(const float4*)&OutL[bb][q * 8 + 4];
    float* dst = partialA + (((size_t)(c * NRCH + rch)) * CB + bb) * COUT + q * 8;
    *(float4*)dst = v0;
    *(float4*)(dst + 4) = v1;
    if (t < 128) partialE[((size_t)(c * NRCH + rch)) * CB + t] = OutL[t][32];
  }
}

// ---------------------------------------------------------------------------
// redv: per (c,b) reduce 256 chunk-partials -> v = squash(s/esum).
// mode: 0 first (vsum = v), 1 mid (vsum += v), 2 final (out = v).
// grid 256 x 256 threads.
// ---------------------------------------------------------------------------
__global__ __launch_bounds__(256) void caps_redv_kernel(
    const float* __restrict__ partialA, const float* __restrict__ partialE,
    float* __restrict__ vsum, float* __restrict__ out, int mode)
{
  const int cb = (int)blockIdx.x;
  const int c  = cb >> 7, b = cb & 127;
  const int t  = (int)threadIdx.x;
  const int o  = t & 31, jg = t >> 5;      // 8 j-groups

  __shared__ float red[8][33];
  __shared__ float rede[8];

  float s = 0.f;
#pragma unroll 4
  for (int k = 0; k < 32; ++k) {
    const int j = jg + k * 8;
    s += partialA[(((size_t)(c * NRCH + j)) * CB + b) * COUT + o];
  }
  red[jg][o] = s;
  __syncthreads();

  if (t < 8) {
    float e = 0.f;
#pragma unroll 4
    for (int k = 0; k < 32; ++k)
      e += partialE[((size_t)(c * NRCH + t + k * 8)) * CB + b];
    rede[t] = e;
  }
  __syncthreads();

  if (t < 32) {
    float sv = red[0][t] + red[1][t] + red[2][t] + red[3][t] +
               red[4][t] + red[5][t] + red[6][t] + red[7][t];
    float es = rede[0] + rede[1] + rede[2] + rede[3] +
               rede[4] + rede[5] + rede[6] + rede[7];
    float sm = sv / es;
    float sn = sm * sm;
#pragma unroll
    for (int sh = 1; sh < 32; sh <<= 1) sn += __shfl_xor(sn, sh);
    float fac = sn / ((1.f + sn + EPSF) * sqrtf(sn + EPSF));
    float vv = sm * fac;
    if (mode == 2)      out[cb * COUT + t]  = vv;
    else if (mode == 1) vsum[cb * COUT + t] += vv;
    else                vsum[cb * COUT + t] = vv;
  }
}

extern "C" void kernel_launch(void* const* d_in, const int* in_sizes, int n_in,
                              void* d_out, int out_size, void* d_ws, size_t ws_size,
                              hipStream_t stream) {
  const float* x = (const float*)d_in[0];
  const float* w = (const float*)d_in[1];
  float* out = (float*)d_out;

  char* p = (char*)d_ws;
  float* vsum = (float*)p;                         // 32,768 B
  p += (size_t)CCAP * CB * COUT * sizeof(float);
  float* partialA = (float*)p;                     // 8,388,608 B
  p += (size_t)CCAP * NRCH * CB * COUT * sizeof(float);
  float* partialE = (float*)p;                     // 262,144 B

  for (int it = 0; it < 3; ++it) {
    caps_pass_kernel<<<dim3(CCAP * NRCH), 512, 0, stream>>>(
        x, w, vsum, partialA, partialE, it == 0 ? 1 : 0);
    caps_redv_kernel<<<dim3(CCAP * CB), 256, 0, stream>>>(
        partialA, partialE, vsum, out, it == 0 ? 0 : (it == 1 ? 1 : 2));
  }
}